// Round 1
// baseline (167.552 us; speedup 1.0000x reference)
//
#include <hip/hip_runtime.h>
#include <hip/hip_bf16.h>

typedef __attribute__((ext_vector_type(8))) short short8;
typedef __attribute__((ext_vector_type(4))) float f32x4;
using bf16 = __hip_bfloat16;

__device__ __forceinline__ unsigned short f2bf(float f) {
    unsigned u = __float_as_uint(f);
    u += 0x7fff + ((u >> 16) & 1);           // round-to-nearest-even
    return (unsigned short)(u >> 16);
}

// ---------------------------------------------------------------- convert
__global__ __launch_bounds__(256) void cvt_kernel(
    const float* __restrict__ x, const float* __restrict__ wq, const float* __restrict__ wk,
    const float* __restrict__ wv, const float* __restrict__ wo,
    bf16* __restrict__ xb, bf16* __restrict__ wqb, bf16* __restrict__ wkb,
    bf16* __restrict__ wvb, bf16* __restrict__ wob)
{
    int y = blockIdx.y;
    const float* src; bf16* dst; int n;
    if (y == 0)      { src = x;  dst = xb;  n = 4096 * 512; }
    else if (y == 1) { src = wq; dst = wqb; n = 512 * 512; }
    else if (y == 2) { src = wk; dst = wkb; n = 512 * 512; }
    else if (y == 3) { src = wv; dst = wvb; n = 512 * 512; }
    else             { src = wo; dst = wob; n = 512 * 512; }
    int i4 = (blockIdx.x * 256 + threadIdx.x) * 4;
    if (i4 >= n) return;
    float4 v = *(const float4*)(src + i4);
    ushort4 u;
    u.x = f2bf(v.x); u.y = f2bf(v.y); u.z = f2bf(v.z); u.w = f2bf(v.w);
    *(ushort4*)(dst + i4) = u;
}

// ---------------------------------------------------------------- bf16 MFMA GEMM
// Out(z) = act( A(4096x512) @ W(z)(512x512)^T + b(z) ),  W row-major [n][k] so both
// A and W tiles stage identically (rows x 32 k).  Tile 128x128, 4 waves, each wave
// 64x64 via 4x4 MFMA 16x16x32 tiles.
__global__ __launch_bounds__(256) void gemm3_kernel(
    const bf16* __restrict__ A,
    const bf16* __restrict__ W0, const bf16* __restrict__ W1, const bf16* __restrict__ W2,
    const float* __restrict__ b0, const float* __restrict__ b1, const float* __restrict__ b2,
    float* __restrict__ O0, float* __restrict__ O1, float* __restrict__ O2,
    int nrelu)
{
    __shared__ bf16 As[128 * 40];   // stride 40 bf16 = 80B: 16B-aligned, bank-spread
    __shared__ bf16 Bs[128 * 40];
    int z = blockIdx.z;
    const bf16* W = (z == 0) ? W0 : ((z == 1) ? W1 : W2);
    const float* bias = (z == 0) ? b0 : ((z == 1) ? b1 : b2);
    float* Out = (z == 0) ? O0 : ((z == 1) ? O1 : O2);
    bool relu = z < nrelu;

    int m0 = blockIdx.x * 128;
    int n0 = blockIdx.y * 128;
    int tid = threadIdx.x;
    int lane = tid & 63;
    int wave = tid >> 6;
    int wm = (wave >> 1) * 64;
    int wn = (wave & 1) * 64;

    f32x4 zero4 = {0.f, 0.f, 0.f, 0.f};
    f32x4 acc[4][4];
    #pragma unroll
    for (int t = 0; t < 4; ++t)
        #pragma unroll
        for (int u = 0; u < 4; ++u) acc[t][u] = zero4;

    int srow = tid >> 2;            // 0..63
    int skk  = (tid & 3) * 8;       // 0,8,16,24

    for (int k0 = 0; k0 < 512; k0 += 32) {
        __syncthreads();
        #pragma unroll
        for (int rep = 0; rep < 2; ++rep) {
            int r = rep * 64 + srow;
            *(uint4*)&As[r * 40 + skk] = *(const uint4*)&A[(size_t)(m0 + r) * 512 + k0 + skk];
            *(uint4*)&Bs[r * 40 + skk] = *(const uint4*)&W[(size_t)(n0 + r) * 512 + k0 + skk];
        }
        __syncthreads();
        int fr = lane & 15;
        int q  = lane >> 4;
        short8 af[4], bfr[4];
        #pragma unroll
        for (int t = 0; t < 4; ++t) af[t] = *(const short8*)&As[(wm + t * 16 + fr) * 40 + q * 8];
        #pragma unroll
        for (int u = 0; u < 4; ++u) bfr[u] = *(const short8*)&Bs[(wn + u * 16 + fr) * 40 + q * 8];
        #pragma unroll
        for (int t = 0; t < 4; ++t)
            #pragma unroll
            for (int u = 0; u < 4; ++u)
                acc[t][u] = __builtin_amdgcn_mfma_f32_16x16x32_bf16(af[t], bfr[u], acc[t][u], 0, 0, 0);
    }

    int col = lane & 15;
    int rb  = (lane >> 4) * 4;
    #pragma unroll
    for (int t = 0; t < 4; ++t) {
        #pragma unroll
        for (int u = 0; u < 4; ++u) {
            int gn = n0 + wn + u * 16 + col;
            float bv = bias[gn];
            #pragma unroll
            for (int r = 0; r < 4; ++r) {
                int gm = m0 + wm + t * 16 + rb + r;
                float v = acc[t][u][r] + bv;
                if (relu) v = fmaxf(v, 0.f);
                Out[(size_t)gm * 512 + gn] = v;
            }
        }
    }
}

// ---------------------------------------------------------------- row L2 norm (in place)
__global__ __launch_bounds__(64) void l2norm_kernel(float* __restrict__ Q, float* __restrict__ K)
{
    float* row = (blockIdx.y ? K : Q) + (size_t)blockIdx.x * 512;
    int lane = threadIdx.x;
    float4 a = ((const float4*)row)[lane];
    float4 c = ((const float4*)row)[lane + 64];
    float s = a.x*a.x + a.y*a.y + a.z*a.z + a.w*a.w
            + c.x*c.x + c.y*c.y + c.z*c.z + c.w*c.w;
    #pragma unroll
    for (int off = 32; off > 0; off >>= 1) s += __shfl_xor(s, off, 64);
    float scale = 1.f / fmaxf(sqrtf(s), 1e-12f);
    a.x *= scale; a.y *= scale; a.z *= scale; a.w *= scale;
    c.x *= scale; c.y *= scale; c.z *= scale; c.w *= scale;
    ((float4*)row)[lane] = a;
    ((float4*)row)[lane + 64] = c;
}

// ---------------------------------------------------------------- per-chunk KV sums
// Sc[n][c][d][m] = sum_{j in chunk c} K[n,j,d] * V[n,j,m]   (chunk = 128 seq positions)
__global__ __launch_bounds__(256) void chunk_kv_kernel(
    const float* __restrict__ Kf, const float* __restrict__ Vf, float* __restrict__ Sc)
{
    int n = blockIdx.x >> 4, c = blockIdx.x & 15;
    int b = n >> 3, h = n & 7;
    __shared__ float Ks[64 * 64];
    __shared__ float Vs[64 * 64];
    int tid = threadIdx.x;
    int td = tid >> 4, tm = tid & 15;
    int d0 = td * 4, m0 = tm * 4;
    float acc[4][4] = {};
    for (int half = 0; half < 2; ++half) {
        __syncthreads();
        #pragma unroll
        for (int rep = 0; rep < 4; ++rep) {
            int idx = rep * 1024 + tid * 4;
            int j = idx >> 6, d = idx & 63;
            int grow = (c * 128 + half * 64 + j) * 2 + b;
            *(float4*)&Ks[j * 64 + d] = *(const float4*)&Kf[(size_t)grow * 512 + h * 64 + d];
            *(float4*)&Vs[j * 64 + d] = *(const float4*)&Vf[(size_t)grow * 512 + h * 64 + d];
        }
        __syncthreads();
        for (int j = 0; j < 64; ++j) {
            float4 kv = *(const float4*)&Ks[j * 64 + d0];
            float4 vv = *(const float4*)&Vs[j * 64 + m0];
            acc[0][0] += kv.x*vv.x; acc[0][1] += kv.x*vv.y; acc[0][2] += kv.x*vv.z; acc[0][3] += kv.x*vv.w;
            acc[1][0] += kv.y*vv.x; acc[1][1] += kv.y*vv.y; acc[1][2] += kv.y*vv.z; acc[1][3] += kv.y*vv.w;
            acc[2][0] += kv.z*vv.x; acc[2][1] += kv.z*vv.y; acc[2][2] += kv.z*vv.z; acc[2][3] += kv.z*vv.w;
            acc[3][0] += kv.w*vv.x; acc[3][1] += kv.w*vv.y; acc[3][2] += kv.w*vv.z; acc[3][3] += kv.w*vv.w;
        }
    }
    float* out = Sc + (size_t)blockIdx.x * 4096;
    #pragma unroll
    for (int i = 0; i < 4; ++i)
        #pragma unroll
        for (int j2 = 0; j2 < 4; ++j2)
            out[(d0 + i) * 64 + m0 + j2] = acc[i][j2];
}

// ---------------------------------------------------------------- exclusive chunk prefix
__global__ __launch_bounds__(256) void prefix_kernel(const float* __restrict__ Sc, float* __restrict__ Sp)
{
    int n = blockIdx.x >> 4;
    int e = ((blockIdx.x & 15) << 8) + threadIdx.x;
    size_t base = (size_t)n * 16 * 4096 + e;
    float run = 0.f;
    #pragma unroll
    for (int c = 0; c < 16; ++c) {
        size_t off = base + (size_t)c * 4096;
        Sp[off] = run;
        run += Sc[off];
    }
}

// ---------------------------------------------------------------- causal attention within chunk
// out[l] = Q[l] @ Sprev(c)  +  sum_{j<=l, same chunk} (Q[l].K[j]) V[j];  writes bf16 AO.
__global__ __launch_bounds__(256) void attn_kernel(
    const float* __restrict__ Qf, const float* __restrict__ Kf, const float* __restrict__ Vf,
    const float* __restrict__ Sp, bf16* __restrict__ AOb)
{
    int n = blockIdx.x >> 4, c = blockIdx.x & 15;
    int b = n >> 3, h = n & 7;
    __shared__ float Qs[128 * 68];   // padded stride 68 (16B-aligned rows)
    __shared__ float Ks[16 * 64];
    __shared__ float Vs[16 * 64];
    __shared__ float PS[4096];       // Sprev staging, then P tiles (stride 18)
    int tid = threadIdx.x;

    #pragma unroll
    for (int rep = 0; rep < 8; ++rep) {
        int idx = rep * 1024 + tid * 4;
        int l = idx >> 6, d = idx & 63;
        int grow = (c * 128 + l) * 2 + b;
        *(float4*)&Qs[l * 68 + d] = *(const float4*)&Qf[(size_t)grow * 512 + h * 64 + d];
    }
    const float* sp = Sp + (size_t)blockIdx.x * 4096;
    #pragma unroll
    for (int rep = 0; rep < 4; ++rep) {
        int idx = rep * 1024 + tid * 4;
        *(float4*)&PS[idx] = *(const float4*)&sp[idx];
    }
    __syncthreads();

    int lg = tid >> 3;        // owns rows l = lg*4 .. lg*4+3
    int mq = tid & 7;         // owns cols m = mq*8 .. mq*8+7
    float acc[4][8];
    #pragma unroll
    for (int i = 0; i < 4; ++i)
        #pragma unroll
        for (int j2 = 0; j2 < 8; ++j2) acc[i][j2] = 0.f;

    // out += Q @ Sprev
    for (int d4 = 0; d4 < 16; ++d4) {
        float4 q4[4];
        #pragma unroll
        for (int il = 0; il < 4; ++il)
            q4[il] = *(const float4*)&Qs[(lg * 4 + il) * 68 + d4 * 4];
        #pragma unroll
        for (int ci = 0; ci < 4; ++ci) {
            #pragma unroll
            for (int m4 = 0; m4 < 2; ++m4) {
                float4 s4 = *(const float4*)&PS[(d4 * 4 + ci) * 64 + mq * 8 + m4 * 4];
                #pragma unroll
                for (int il = 0; il < 4; ++il) {
                    float qv = (ci == 0) ? q4[il].x : (ci == 1) ? q4[il].y
                             : (ci == 2) ? q4[il].z : q4[il].w;
                    acc[il][m4*4+0] += qv * s4.x;
                    acc[il][m4*4+1] += qv * s4.y;
                    acc[il][m4*4+2] += qv * s4.z;
                    acc[il][m4*4+3] += qv * s4.w;
                }
            }
        }
    }

    int pl = tid >> 1;        // P-stage: row
    int pj = tid & 1;         // P-stage: j half (8 each)

    for (int jt = 0; jt < 8; ++jt) {
        __syncthreads();      // protects Ks/Vs (prev PV) and PS (prev reads)
        {
            int idx = tid * 4;
            int j = idx >> 6, d = idx & 63;
            int grow = (c * 128 + jt * 16 + j) * 2 + b;
            *(float4*)&Ks[j * 64 + d] = *(const float4*)&Kf[(size_t)grow * 512 + h * 64 + d];
            *(float4*)&Vs[j * 64 + d] = *(const float4*)&Vf[(size_t)grow * 512 + h * 64 + d];
        }
        __syncthreads();
        // P[l][j] = Q[l].K[j]  (masked causal), 16-wide j subtile
        float pacc[8];
        #pragma unroll
        for (int jj = 0; jj < 8; ++jj) pacc[jj] = 0.f;
        for (int d4 = 0; d4 < 16; ++d4) {
            float4 q4 = *(const float4*)&Qs[pl * 68 + d4 * 4];
            #pragma unroll
            for (int jj = 0; jj < 8; ++jj) {
                float4 k4 = *(const float4*)&Ks[(pj * 8 + jj) * 64 + d4 * 4];
                pacc[jj] += q4.x*k4.x + q4.y*k4.y + q4.z*k4.z + q4.w*k4.w;
            }
        }
        #pragma unroll
        for (int jj = 0; jj < 8; ++jj) {
            int jl = jt * 16 + pj * 8 + jj;
            PS[pl * 18 + pj * 8 + jj] = (jl <= pl) ? pacc[jj] : 0.f;
        }
        __syncthreads();
        // out += P @ V subtile
        if (lg * 4 + 3 >= jt * 16) {
            for (int j = 0; j < 16; ++j) {
                float4 v4a = *(const float4*)&Vs[j * 64 + mq * 8];
                float4 v4b = *(const float4*)&Vs[j * 64 + mq * 8 + 4];
                #pragma unroll
                for (int il = 0; il < 4; ++il) {
                    float p = PS[(lg * 4 + il) * 18 + j];
                    acc[il][0] += p * v4a.x; acc[il][1] += p * v4a.y;
                    acc[il][2] += p * v4a.z; acc[il][3] += p * v4a.w;
                    acc[il][4] += p * v4b.x; acc[il][5] += p * v4b.y;
                    acc[il][6] += p * v4b.z; acc[il][7] += p * v4b.w;
                }
            }
        }
    }

    #pragma unroll
    for (int il = 0; il < 4; ++il) {
        int grow = (c * 128 + lg * 4 + il) * 2 + b;
        bf16* dst = AOb + (size_t)grow * 512 + h * 64 + mq * 8;
        ushort4 u0, u1;
        u0.x = f2bf(acc[il][0]); u0.y = f2bf(acc[il][1]);
        u0.z = f2bf(acc[il][2]); u0.w = f2bf(acc[il][3]);
        u1.x = f2bf(acc[il][4]); u1.y = f2bf(acc[il][5]);
        u1.z = f2bf(acc[il][6]); u1.w = f2bf(acc[il][7]);
        *(ushort4*)(dst)     = u0;
        *(ushort4*)(dst + 4) = u1;
    }
}

// ---------------------------------------------------------------- launch
extern "C" void kernel_launch(void* const* d_in, const int* in_sizes, int n_in,
                              void* d_out, int out_size, void* d_ws, size_t ws_size,
                              hipStream_t stream)
{
    (void)in_sizes; (void)n_in; (void)out_size; (void)ws_size;
    const float* x  = (const float*)d_in[0];
    const float* Wq = (const float*)d_in[1];
    const float* bq = (const float*)d_in[2];
    const float* Wk = (const float*)d_in[3];
    const float* bk = (const float*)d_in[4];
    const float* Wv = (const float*)d_in[5];
    const float* bv = (const float*)d_in[6];
    const float* Wo = (const float*)d_in[7];
    const float* bo = (const float*)d_in[8];
    float* out = (float*)d_out;

    // workspace layout (~44 MB)
    bf16* Xb  = (bf16*)d_ws;          // 4096*512
    bf16* Wqb = Xb + 2097152;         // 512*512 each
    bf16* Wkb = Wqb + 262144;
    bf16* Wvb = Wkb + 262144;
    bf16* Wob = Wvb + 262144;
    float* Qf = (float*)(Wob + 262144);  // 4096*512 f32 each
    float* Kf = Qf + 2097152;
    float* Vf = Kf + 2097152;
    float* Sc = Vf + 2097152;            // 16*16*64*64 f32
    float* Sp = Sc + 1048576;
    bf16* AOb = (bf16*)(Sp + 1048576);   // 4096*512 bf16

    cvt_kernel<<<dim3(2048, 5), 256, 0, stream>>>(x, Wq, Wk, Wv, Wo, Xb, Wqb, Wkb, Wvb, Wob);
    gemm3_kernel<<<dim3(32, 4, 3), 256, 0, stream>>>(Xb, Wqb, Wkb, Wvb, bq, bk, bv, Qf, Kf, Vf, 2);
    l2norm_kernel<<<dim3(4096, 2), 64, 0, stream>>>(Qf, Kf);
    chunk_kv_kernel<<<dim3(256), 256, 0, stream>>>(Kf, Vf, Sc);
    prefix_kernel<<<dim3(256), 256, 0, stream>>>(Sc, Sp);
    attn_kernel<<<dim3(256), 256, 0, stream>>>(Qf, Kf, Vf, Sp, AOb);
    gemm3_kernel<<<dim3(32, 4, 1), 256, 0, stream>>>(AOb, Wob, Wob, Wob, bo, bo, bo, out, out, out, 0);
}

// Round 2
// 130.632 us; speedup vs baseline: 1.2826x; 1.2826x over previous
//
#include <hip/hip_runtime.h>
#include <hip/hip_bf16.h>

typedef __attribute__((ext_vector_type(8))) short short8;
typedef __attribute__((ext_vector_type(4))) float f32x4;
using bf16 = __hip_bfloat16;

__device__ __forceinline__ unsigned short f2bf(float f) {
    unsigned u = __float_as_uint(f);
    u += 0x7fff + ((u >> 16) & 1);           // round-to-nearest-even
    return (unsigned short)(u >> 16);
}

// ---------------------------------------------------------------- convert fp32 -> bf16
__global__ __launch_bounds__(256) void cvt_kernel(
    const float* __restrict__ x, const float* __restrict__ wq, const float* __restrict__ wk,
    const float* __restrict__ wv, const float* __restrict__ wo,
    bf16* __restrict__ xb, bf16* __restrict__ wqb, bf16* __restrict__ wkb,
    bf16* __restrict__ wvb, bf16* __restrict__ wob)
{
    int y = blockIdx.y;
    const float* src; bf16* dst; int n;
    if (y == 0)      { src = x;  dst = xb;  n = 4096 * 512; }
    else if (y == 1) { src = wq; dst = wqb; n = 512 * 512; }
    else if (y == 2) { src = wk; dst = wkb; n = 512 * 512; }
    else if (y == 3) { src = wv; dst = wvb; n = 512 * 512; }
    else             { src = wo; dst = wob; n = 512 * 512; }
    int i4 = (blockIdx.x * 256 + threadIdx.x) * 4;
    if (i4 >= n) return;
    float4 v = *(const float4*)(src + i4);
    ushort4 u;
    u.x = f2bf(v.x); u.y = f2bf(v.y); u.z = f2bf(v.z); u.w = f2bf(v.w);
    *(ushort4*)((unsigned short*)dst + i4) = u;
}

// ---------------------------------------------------------------- bf16 MFMA GEMM, tile 64 x TN
// Out(z) = act( A(4096x512) @ W(z)(512x512)^T + b(z) ).  4 waves, each 32 x TN/2.
template<int TN>
__global__ __launch_bounds__(256) void gemm_kernel(
    const bf16* __restrict__ A,
    const bf16* __restrict__ W0, const bf16* __restrict__ W1, const bf16* __restrict__ W2,
    const float* __restrict__ b0, const float* __restrict__ b1, const float* __restrict__ b2,
    float* __restrict__ O0, float* __restrict__ O1, float* __restrict__ O2,
    int nrelu)
{
    constexpr int NT = TN / 32;              // n-tiles of 16 per wave
    __shared__ bf16 As[64 * 40];
    __shared__ bf16 Bs[TN * 40];
    int z = blockIdx.z;
    const bf16* W = (z == 0) ? W0 : ((z == 1) ? W1 : W2);
    const float* bias = (z == 0) ? b0 : ((z == 1) ? b1 : b2);
    float* Out = (z == 0) ? O0 : ((z == 1) ? O1 : O2);
    bool relu = z < nrelu;

    int m0 = blockIdx.x * 64;
    int n0 = blockIdx.y * TN;
    int tid = threadIdx.x;
    int lane = tid & 63;
    int wave = tid >> 6;
    int wm = (wave >> 1) * 32;
    int wn = (wave & 1) * (TN / 2);

    f32x4 zero4 = {0.f, 0.f, 0.f, 0.f};
    f32x4 acc[2][NT];
    #pragma unroll
    for (int t = 0; t < 2; ++t)
        #pragma unroll
        for (int u = 0; u < NT; ++u) acc[t][u] = zero4;

    int srow = tid >> 2;            // 0..63
    int skk  = (tid & 3) * 8;       // 0,8,16,24

    for (int k0 = 0; k0 < 512; k0 += 32) {
        __syncthreads();
        *(uint4*)&As[srow * 40 + skk] = *(const uint4*)((const unsigned short*)A + (size_t)(m0 + srow) * 512 + k0 + skk);
        #pragma unroll
        for (int rep = 0; rep < TN / 64; ++rep) {
            int r = rep * 64 + srow;
            *(uint4*)&Bs[r * 40 + skk] = *(const uint4*)((const unsigned short*)W + (size_t)(n0 + r) * 512 + k0 + skk);
        }
        __syncthreads();
        int fr = lane & 15;
        int q  = lane >> 4;
        short8 af[2], bfr[NT];
        #pragma unroll
        for (int t = 0; t < 2; ++t) af[t] = *(const short8*)&As[(wm + t * 16 + fr) * 40 + q * 8];
        #pragma unroll
        for (int u = 0; u < NT; ++u) bfr[u] = *(const short8*)&Bs[(wn + u * 16 + fr) * 40 + q * 8];
        #pragma unroll
        for (int t = 0; t < 2; ++t)
            #pragma unroll
            for (int u = 0; u < NT; ++u)
                acc[t][u] = __builtin_amdgcn_mfma_f32_16x16x32_bf16(af[t], bfr[u], acc[t][u], 0, 0, 0);
    }

    int col = lane & 15;
    int rb  = (lane >> 4) * 4;
    #pragma unroll
    for (int t = 0; t < 2; ++t) {
        #pragma unroll
        for (int u = 0; u < NT; ++u) {
            int gn = n0 + wn + u * 16 + col;
            float bv = bias[gn];
            #pragma unroll
            for (int r = 0; r < 4; ++r) {
                int gm = m0 + wm + t * 16 + rb + r;
                float v = acc[t][u][r] + bv;
                if (relu) v = fmaxf(v, 0.f);
                Out[(size_t)gm * 512 + gn] = v;
            }
        }
    }
}

// ---------------------------------------------------------------- row L2 norm -> bf16 (K also fp32 in place)
__global__ __launch_bounds__(256) void l2norm_kernel(
    const float* __restrict__ Qf, float* __restrict__ Kf,
    bf16* __restrict__ Qb, bf16* __restrict__ Kb)
{
    int row = blockIdx.x * 4 + (threadIdx.x >> 6);
    int lane = threadIdx.x & 63;
    bool isK = (blockIdx.y != 0);
    const float* src = (isK ? (const float*)Kf : Qf) + (size_t)row * 512;
    float4 a = ((const float4*)src)[lane];
    float4 cc = ((const float4*)src)[lane + 64];
    float s = a.x*a.x + a.y*a.y + a.z*a.z + a.w*a.w
            + cc.x*cc.x + cc.y*cc.y + cc.z*cc.z + cc.w*cc.w;
    #pragma unroll
    for (int off = 32; off > 0; off >>= 1) s += __shfl_xor(s, off, 64);
    float scale = 1.f / fmaxf(sqrtf(s), 1e-12f);
    a.x *= scale; a.y *= scale; a.z *= scale; a.w *= scale;
    cc.x *= scale; cc.y *= scale; cc.z *= scale; cc.w *= scale;
    unsigned short* dstb = (unsigned short*)(isK ? Kb : Qb) + (size_t)row * 512;
    ushort4 u0, u1;
    u0.x = f2bf(a.x);  u0.y = f2bf(a.y);  u0.z = f2bf(a.z);  u0.w = f2bf(a.w);
    u1.x = f2bf(cc.x); u1.y = f2bf(cc.y); u1.z = f2bf(cc.z); u1.w = f2bf(cc.w);
    *(ushort4*)&dstb[lane * 4] = u0;
    *(ushort4*)&dstb[256 + lane * 4] = u1;
    if (isK) {
        float* wb = Kf + (size_t)row * 512;
        ((float4*)wb)[lane] = a;
        ((float4*)wb)[lane + 64] = cc;
    }
}

// ---------------------------------------------------------------- per-chunk KV sums (transposed out) + V^T bf16
// ScT[n][c][m][d] = sum_{j in chunk c} K[n,j,d] * V[n,j,m];  Vt_g[n][m][l] = V[n,l,m]
__global__ __launch_bounds__(256) void chunk_kv_kernel(
    const float* __restrict__ Kf, const float* __restrict__ Vf,
    float* __restrict__ ScT, bf16* __restrict__ Vt_g)
{
    int n = blockIdx.x >> 4, c = blockIdx.x & 15;
    int b = n >> 3, h = n & 7;
    __shared__ float Ks[64 * 64];
    __shared__ float Vs[64 * 64];
    int tid = threadIdx.x;
    int td = tid >> 4, tm = tid & 15;
    int d0 = td * 4, m0 = tm * 4;
    int vm = tid & 63, vj0 = (tid >> 6) * 16;
    float acc[4][4] = {};
    for (int half = 0; half < 2; ++half) {
        __syncthreads();
        #pragma unroll
        for (int rep = 0; rep < 4; ++rep) {
            int idx = rep * 1024 + tid * 4;
            int j = idx >> 6, d = idx & 63;
            int grow = (c * 128 + half * 64 + j) * 2 + b;
            *(float4*)&Ks[j * 64 + d] = *(const float4*)&Kf[(size_t)grow * 512 + h * 64 + d];
            *(float4*)&Vs[j * 64 + d] = *(const float4*)&Vf[(size_t)grow * 512 + h * 64 + d];
        }
        __syncthreads();
        for (int j = 0; j < 64; ++j) {
            float4 kv = *(const float4*)&Ks[j * 64 + d0];
            float4 vv = *(const float4*)&Vs[j * 64 + m0];
            acc[0][0] += kv.x*vv.x; acc[0][1] += kv.x*vv.y; acc[0][2] += kv.x*vv.z; acc[0][3] += kv.x*vv.w;
            acc[1][0] += kv.y*vv.x; acc[1][1] += kv.y*vv.y; acc[1][2] += kv.y*vv.z; acc[1][3] += kv.y*vv.w;
            acc[2][0] += kv.z*vv.x; acc[2][1] += kv.z*vv.y; acc[2][2] += kv.z*vv.z; acc[2][3] += kv.z*vv.w;
            acc[3][0] += kv.w*vv.x; acc[3][1] += kv.w*vv.y; acc[3][2] += kv.w*vv.z; acc[3][3] += kv.w*vv.w;
        }
        // emit V^T bf16 for this half
        unsigned short tmp[16];
        #pragma unroll
        for (int i = 0; i < 16; ++i) tmp[i] = f2bf(Vs[(vj0 + i) * 64 + vm]);
        size_t vtoff = (size_t)n * 131072 + (size_t)vm * 2048 + c * 128 + half * 64 + vj0;
        *(uint4*)((unsigned short*)Vt_g + vtoff)     = *(uint4*)&tmp[0];
        *(uint4*)((unsigned short*)Vt_g + vtoff + 8) = *(uint4*)&tmp[8];
    }
    float* outp = ScT + (size_t)blockIdx.x * 4096;
    #pragma unroll
    for (int j2 = 0; j2 < 4; ++j2) {
        float4 o4 = make_float4(acc[0][j2], acc[1][j2], acc[2][j2], acc[3][j2]);
        *(float4*)&outp[(m0 + j2) * 64 + d0] = o4;
    }
}

// ---------------------------------------------------------------- exclusive chunk prefix -> SpT bf16
// SpT[n][c][m*64+d] = sum_{c'<c} ScT[n][c'][m*64+d]
__global__ __launch_bounds__(256) void prefix_kernel(const float* __restrict__ ScT, bf16* __restrict__ SpT)
{
    int n = blockIdx.x >> 4;
    int idx = ((blockIdx.x & 15) << 8) + threadIdx.x;   // 0..4095 within plane
    size_t base = (size_t)n * 65536 + idx;
    unsigned short* sp = (unsigned short*)SpT;
    float run = 0.f;
    #pragma unroll
    for (int c = 0; c < 16; ++c) {
        size_t off = base + (size_t)c * 4096;
        sp[off] = f2bf(run);
        run += ScT[off];
    }
}

// ---------------------------------------------------------------- MFMA causal linear attention per (head, chunk)
// out[l] = Q[l] @ Sprev + sum_{j<=l in chunk} (Q[l].K[j]) V[j]
__global__ __launch_bounds__(256) void attn_kernel(
    const bf16* __restrict__ Qb, const bf16* __restrict__ Kb,
    const bf16* __restrict__ Vt_g, const bf16* __restrict__ SpT_g,
    bf16* __restrict__ AOb)
{
    int n = blockIdx.x >> 4, c = blockIdx.x & 15;
    int b = n >> 3, h = n & 7;
    __shared__ unsigned short Qs[128 * 72];   // [l][d]
    __shared__ unsigned short Ks[128 * 72];   // [j][d]
    __shared__ unsigned short Vt[64 * 136];   // [m][j]
    __shared__ unsigned short Ps[4 * 32 * 40];// per-wave P [l_loc][j_loc]
    int tid = threadIdx.x;
    int lane = tid & 63;
    int w = tid >> 6;

    #pragma unroll
    for (int rep = 0; rep < 4; ++rep) {
        int idx = rep * 256 + tid;
        int l = idx >> 3, dc = (idx & 7) * 8;
        int grow = (c * 128 + l) * 2 + b;
        size_t goff = (size_t)grow * 512 + h * 64 + dc;
        *(uint4*)&Qs[l * 72 + dc] = *(const uint4*)((const unsigned short*)Qb + goff);
        *(uint4*)&Ks[l * 72 + dc] = *(const uint4*)((const unsigned short*)Kb + goff);
    }
    #pragma unroll
    for (int rep = 0; rep < 4; ++rep) {
        int idx = rep * 256 + tid;
        int m = idx >> 4, jc = (idx & 15) * 8;
        *(uint4*)&Vt[m * 136 + jc] =
            *(const uint4*)((const unsigned short*)Vt_g + (size_t)n * 131072 + (size_t)m * 2048 + c * 128 + jc);
    }
    __syncthreads();

    int fr = lane & 15, q = lane >> 4;
    // Q fragments: rows w*32 .. w*32+31, k = full 64 d in two halves
    short8 qf[2][2];
    #pragma unroll
    for (int lt = 0; lt < 2; ++lt)
        #pragma unroll
        for (int kh = 0; kh < 2; ++kh)
            qf[lt][kh] = *(const short8*)&Qs[(w * 32 + lt * 16 + fr) * 72 + kh * 32 + q * 8];

    f32x4 zero4 = {0.f, 0.f, 0.f, 0.f};
    f32x4 oacc[2][4];
    #pragma unroll
    for (int lt = 0; lt < 2; ++lt)
        #pragma unroll
        for (int mt = 0; mt < 4; ++mt) oacc[lt][mt] = zero4;

    // O = Q @ Sprev^T  (SpT read straight from global, L2-hot)
    const unsigned short* spg = (const unsigned short*)SpT_g + (size_t)blockIdx.x * 4096;
    #pragma unroll
    for (int mt = 0; mt < 4; ++mt) {
        #pragma unroll
        for (int kh = 0; kh < 2; ++kh) {
            short8 sf = *(const short8*)&spg[(mt * 16 + fr) * 64 + kh * 32 + q * 8];
            oacc[0][mt] = __builtin_amdgcn_mfma_f32_16x16x32_bf16(qf[0][kh], sf, oacc[0][mt], 0, 0, 0);
            oacc[1][mt] = __builtin_amdgcn_mfma_f32_16x16x32_bf16(qf[1][kh], sf, oacc[1][mt], 0, 0, 0);
        }
    }

    unsigned short* myPs = &Ps[w * 1280];
    int col = fr, rbase = q * 4;
    for (int jt = 0; jt <= w; ++jt) {             // wave-uniform bound; no barriers inside
        f32x4 pacc[2][2];
        pacc[0][0] = zero4; pacc[0][1] = zero4; pacc[1][0] = zero4; pacc[1][1] = zero4;
        #pragma unroll
        for (int jt16 = 0; jt16 < 2; ++jt16) {
            #pragma unroll
            for (int kh = 0; kh < 2; ++kh) {
                short8 kf = *(const short8*)&Ks[(jt * 32 + jt16 * 16 + fr) * 72 + kh * 32 + q * 8];
                pacc[0][jt16] = __builtin_amdgcn_mfma_f32_16x16x32_bf16(qf[0][kh], kf, pacc[0][jt16], 0, 0, 0);
                pacc[1][jt16] = __builtin_amdgcn_mfma_f32_16x16x32_bf16(qf[1][kh], kf, pacc[1][jt16], 0, 0, 0);
            }
        }
        bool diag = (jt == w);
        #pragma unroll
        for (int lt = 0; lt < 2; ++lt)
            #pragma unroll
            for (int jt16 = 0; jt16 < 2; ++jt16)
                #pragma unroll
                for (int r = 0; r < 4; ++r) {
                    int ll = lt * 16 + rbase + r;
                    int jl = jt16 * 16 + col;
                    float pv = pacc[lt][jt16][r];
                    if (diag && jl > ll) pv = 0.f;
                    myPs[ll * 40 + jl] = f2bf(pv);
                }
        short8 pf0 = *(const short8*)&myPs[fr * 40 + q * 8];
        short8 pf1 = *(const short8*)&myPs[(16 + fr) * 40 + q * 8];
        #pragma unroll
        for (int mt = 0; mt < 4; ++mt) {
            short8 vf = *(const short8*)&Vt[(mt * 16 + fr) * 136 + jt * 32 + q * 8];
            oacc[0][mt] = __builtin_amdgcn_mfma_f32_16x16x32_bf16(pf0, vf, oacc[0][mt], 0, 0, 0);
            oacc[1][mt] = __builtin_amdgcn_mfma_f32_16x16x32_bf16(pf1, vf, oacc[1][mt], 0, 0, 0);
        }
    }

    __syncthreads();                              // all waves done; Qs is dead -> reuse as O staging
    #pragma unroll
    for (int lt = 0; lt < 2; ++lt)
        #pragma unroll
        for (int mt = 0; mt < 4; ++mt)
            #pragma unroll
            for (int r = 0; r < 4; ++r)
                Qs[(w * 32 + lt * 16 + rbase + r) * 72 + mt * 16 + col] = f2bf(oacc[lt][mt][r]);
    __syncthreads();
    #pragma unroll
    for (int rep = 0; rep < 4; ++rep) {
        int idx = rep * 256 + tid;
        int l = idx >> 3, dc = (idx & 7) * 8;
        int grow = (c * 128 + l) * 2 + b;
        *(uint4*)((unsigned short*)AOb + (size_t)grow * 512 + h * 64 + dc) = *(const uint4*)&Qs[l * 72 + dc];
    }
}

// ---------------------------------------------------------------- launch
extern "C" void kernel_launch(void* const* d_in, const int* in_sizes, int n_in,
                              void* d_out, int out_size, void* d_ws, size_t ws_size,
                              hipStream_t stream)
{
    (void)in_sizes; (void)n_in; (void)out_size; (void)ws_size;
    const float* x  = (const float*)d_in[0];
    const float* Wq = (const float*)d_in[1];
    const float* bq = (const float*)d_in[2];
    const float* Wk = (const float*)d_in[3];
    const float* bk = (const float*)d_in[4];
    const float* Wv = (const float*)d_in[5];
    const float* bv = (const float*)d_in[6];
    const float* Wo = (const float*)d_in[7];
    const float* bo = (const float*)d_in[8];
    float* out = (float*)d_out;

    // workspace layout
    bf16* Xb  = (bf16*)d_ws;              // 4096*512
    bf16* Wqb = Xb + 2097152;             // 512*512 each
    bf16* Wkb = Wqb + 262144;
    bf16* Wvb = Wkb + 262144;
    bf16* Wob = Wvb + 262144;
    bf16* Qb  = Wob + 262144;             // 4096*512 bf16
    bf16* Kb  = Qb + 2097152;
    bf16* Vt  = Kb + 2097152;             // 16*64*2048 bf16
    bf16* SpT = Vt + 2097152;             // 16*16*4096 bf16
    bf16* AOb = SpT + 1048576;            // 4096*512 bf16
    float* Qf = (float*)(AOb + 2097152);  // 4096*512 f32 each
    float* Kf = Qf + 2097152;
    float* Vf = Kf + 2097152;
    float* ScT = Vf + 2097152;            // 16*16*4096 f32

    cvt_kernel<<<dim3(2048, 5), 256, 0, stream>>>(x, Wq, Wk, Wv, Wo, Xb, Wqb, Wkb, Wvb, Wob);
    gemm_kernel<128><<<dim3(64, 4, 3), 256, 0, stream>>>(Xb, Wqb, Wkb, Wvb, bq, bk, bv, Qf, Kf, Vf, 2);
    l2norm_kernel<<<dim3(1024, 2), 256, 0, stream>>>(Qf, Kf, Qb, Kb);
    chunk_kv_kernel<<<dim3(256), 256, 0, stream>>>(Kf, Vf, ScT, Vt);
    prefix_kernel<<<dim3(256), 256, 0, stream>>>(ScT, SpT);
    attn_kernel<<<dim3(256), 256, 0, stream>>>(Qb, Kb, Vt, SpT, AOb);
    gemm_kernel<64><<<dim3(64, 8, 1), 256, 0, stream>>>(AOb, Wob, Wob, Wob, bo, bo, bo, out, out, out, 0);
}